// Round 1
// baseline (457.232 us; speedup 1.0000x reference)
//
#include <hip/hip_runtime.h>
#include <hip/hip_bf16.h>

#define BB 4
#define TT 2048
#define DD 1024
#define HH 16
#define HD 64
#define MM (BB*TT)   // 8192

typedef __attribute__((ext_vector_type(8))) _Float16 f16x8;
typedef __attribute__((ext_vector_type(4))) float f32x4;

static __device__ __forceinline__ void gload_lds16(const void* g, void* l) {
  __builtin_amdgcn_global_load_lds((const __attribute__((address_space(1))) void*)g,
                                   (__attribute__((address_space(3))) void*)l, 16, 0, 0);
}

// ---------------- fp32 -> fp16 conversion, 8 elems/thread ----------------
__global__ __launch_bounds__(256) void cvt_f16(const float* __restrict__ in,
                                               _Float16* __restrict__ out, int n8) {
  int i = blockIdx.x * 256 + threadIdx.x;
  if (i >= n8) return;
  const f32x4* p = (const f32x4*)in;
  f32x4 a = p[2*i];
  f32x4 b = p[2*i+1];
  f16x8 r;
  r[0]=(_Float16)a[0]; r[1]=(_Float16)a[1]; r[2]=(_Float16)a[2]; r[3]=(_Float16)a[3];
  r[4]=(_Float16)b[0]; r[5]=(_Float16)b[1]; r[6]=(_Float16)b[2]; r[7]=(_Float16)b[3];
  *(f16x8*)(out + (size_t)8*i) = r;
}

// ------------- W[k][n] fp32 -> Wt[n][k] fp16 (1024x1024), z picks matrix -------------
__global__ __launch_bounds__(256) void transpose_cvt(
    const float* __restrict__ W0, const float* __restrict__ W1,
    const float* __restrict__ W2, const float* __restrict__ W3,
    _Float16* __restrict__ O0, _Float16* __restrict__ O1,
    _Float16* __restrict__ O2, _Float16* __restrict__ O3) {
  const float* W; _Float16* O;
  switch (blockIdx.z) {
    case 0: W = W0; O = O0; break;
    case 1: W = W1; O = O1; break;
    case 2: W = W2; O = O2; break;
    default: W = W3; O = O3; break;
  }
  __shared__ float tile[32][33];
  int bx = blockIdx.x * 32, by = blockIdx.y * 32;
  int tx = threadIdx.x, ty = threadIdx.y;   // (32, 8)
#pragma unroll
  for (int i = 0; i < 4; i++)
    tile[ty + 8*i][tx] = W[(size_t)(by + ty + 8*i) * DD + bx + tx];
  __syncthreads();
#pragma unroll
  for (int i = 0; i < 4; i++)
    O[(size_t)(bx + ty + 8*i) * DD + by + tx] = (_Float16)tile[tx][ty + 8*i];
}

// ---------------- GEMM: C[M][N] = A[M][K] * Bt[N][K]^T + bias ----------------
// 128x128 tile, BK=32, 4 waves (2x2 of 64x64), 16x16x32 fp16 MFMA.
template<bool OUT_F32>
static __device__ __forceinline__ void gemm_body(
    const _Float16* __restrict__ A, const _Float16* __restrict__ Bt,
    const float* __restrict__ bias, void* __restrict__ Cv) {
  const int K = 1024, N = 1024;
  __shared__ __align__(16) _Float16 Alds[128*32];
  __shared__ __align__(16) _Float16 Blds[128*32];
  int tid = threadIdx.x;
  int wid = tid >> 6, lane = tid & 63;
  int m0 = blockIdx.y * 128, n0 = blockIdx.x * 128;
  int wr = wid >> 1, wc = wid & 1;
  int lr = lane & 15, lk = lane >> 4;

  f32x4 zf = {0.f, 0.f, 0.f, 0.f};
  f32x4 acc[4][4];
#pragma unroll
  for (int m = 0; m < 4; m++)
#pragma unroll
    for (int n = 0; n < 4; n++) acc[m][n] = zf;

  // staging: chunk c (0..7) = 1 KiB = 16 rows of 32 cols; wave handles c=2w,2w+1
  int c0 = wid * 2;
  int srow = c0 * 16 + (lane >> 2);
  int skc  = (lane & 3) * 8;
  const _Float16* gA0 = A  + (size_t)(m0 + srow) * K + skc;
  const _Float16* gA1 = gA0 + 16 * K;
  const _Float16* gB0 = Bt + (size_t)(n0 + srow) * K + skc;
  const _Float16* gB1 = gB0 + 16 * K;
  _Float16* lA0 = Alds + c0 * 512;
  _Float16* lA1 = Alds + (c0 + 1) * 512;
  _Float16* lB0 = Blds + c0 * 512;
  _Float16* lB1 = Blds + (c0 + 1) * 512;

  for (int k0 = 0; k0 < K; k0 += 32) {
    __syncthreads();
    gload_lds16(gA0 + k0, lA0);
    gload_lds16(gA1 + k0, lA1);
    gload_lds16(gB0 + k0, lB0);
    gload_lds16(gB1 + k0, lB1);
    __syncthreads();
    f16x8 af[4], bf[4];
#pragma unroll
    for (int m = 0; m < 4; m++)
      af[m] = *(const f16x8*)&Alds[(wr*64 + m*16 + lr)*32 + lk*8];
#pragma unroll
    for (int n = 0; n < 4; n++)
      bf[n] = *(const f16x8*)&Blds[(wc*64 + n*16 + lr)*32 + lk*8];
#pragma unroll
    for (int m = 0; m < 4; m++)
#pragma unroll
      for (int n = 0; n < 4; n++)
        acc[m][n] = __builtin_amdgcn_mfma_f32_16x16x32_f16(af[m], bf[n], acc[m][n], 0, 0, 0);
  }

  // epilogue: C/D layout col = lane&15, row = (lane>>4)*4 + r
#pragma unroll
  for (int n = 0; n < 4; n++) {
    int col = n0 + wc*64 + n*16 + lr;
    float bs = bias[col];
#pragma unroll
    for (int m = 0; m < 4; m++) {
      int row = m0 + wr*64 + m*16 + lk*4;
#pragma unroll
      for (int r = 0; r < 4; r++) {
        float v = acc[m][n][r] + bs;
        if (OUT_F32) ((float*)Cv)[(size_t)(row + r) * N + col] = v;
        else         ((_Float16*)Cv)[(size_t)(row + r) * N + col] = (_Float16)v;
      }
    }
  }
}

__global__ __launch_bounds__(256) void gemm_qkv(
    const _Float16* __restrict__ X,
    const _Float16* __restrict__ WqT, const _Float16* __restrict__ WkT,
    const _Float16* __restrict__ WvT,
    const float* __restrict__ bq, const float* __restrict__ bk,
    const float* __restrict__ bv,
    _Float16* __restrict__ Qo, _Float16* __restrict__ Ko, _Float16* __restrict__ Vo) {
  const _Float16* Bt; const float* bias; _Float16* C;
  if (blockIdx.z == 0)      { Bt = WqT; bias = bq; C = Qo; }
  else if (blockIdx.z == 1) { Bt = WkT; bias = bk; C = Ko; }
  else                      { Bt = WvT; bias = bv; C = Vo; }
  gemm_body<false>(X, Bt, bias, C);
}

__global__ __launch_bounds__(256) void gemm_proj(
    const _Float16* __restrict__ Ain, const _Float16* __restrict__ WpT,
    const float* __restrict__ bp, float* __restrict__ out) {
  gemm_body<true>(Ain, WpT, bp, out);
}

// ---------------- causal flash attention ----------------
// grid: (qtile 0..31, b*h 0..63), 256 threads = 4 waves, each wave owns 16 q-rows.
// KV tiles of 64. Q,K,V,O in [B,T,D] fp16 with head offset h*64.
__global__ __launch_bounds__(256) void attn_fwd(
    const _Float16* __restrict__ Q, const _Float16* __restrict__ Kg,
    const _Float16* __restrict__ Vg, _Float16* __restrict__ O) {
  __shared__ __align__(16) _Float16 Klds[64*72];
  __shared__ __align__(16) _Float16 Vt[64*72];     // [d][j] with block-XOR swizzle
  __shared__ __align__(16) _Float16 Plds[4*16*72]; // per-wave [16][72]
  int qt = blockIdx.x;
  int bh = blockIdx.y;
  int b = bh >> 4, h = bh & 15;
  int tid = threadIdx.x, wid = tid >> 6, lane = tid & 63;
  int lr = lane & 15, lk = lane >> 4;
  size_t base = (size_t)b * TT * DD + h * HD;

  // Q fragments held in registers for the whole kernel (A-frag: row=lane%16, k=8*(lane/16))
  int qrow = qt*64 + wid*16 + lr;
  f16x8 qf0 = *(const f16x8*)&Q[base + (size_t)qrow * DD + lk*8];
  f16x8 qf1 = *(const f16x8*)&Q[base + (size_t)qrow * DD + 32 + lk*8];

  f32x4 zf = {0.f, 0.f, 0.f, 0.f};
  f32x4 o[4];
  o[0] = zf; o[1] = zf; o[2] = zf; o[3] = zf;
  float mrow[4], lsum[4];
#pragma unroll
  for (int r = 0; r < 4; r++) { mrow[r] = -1e30f; lsum[r] = 0.f; }
  const float sc = 0.18033688011112042f;   // (1/sqrt(64)) * log2(e)

  int row0 = tid >> 3, ch = tid & 7;       // staging: 32 rows per pass, 8 chunks/row

  for (int jt = 0; jt <= qt; ++jt) {
    size_t kvbase = base + (size_t)(jt * 64) * DD;
    __syncthreads();
    // stage K (natural, padded) and V^T (block-XOR swizzled) tiles
#pragma unroll
    for (int it = 0; it < 2; ++it) {
      int row = row0 + it * 32;
      f16x8 kv = *(const f16x8*)&Kg[kvbase + (size_t)row * DD + ch*8];
      *(f16x8*)&Klds[row*72 + ch*8] = kv;
      f16x8 vv = *(const f16x8*)&Vg[kvbase + (size_t)row * DD + ch*8];
#pragma unroll
      for (int u = 0; u < 8; ++u) {
        int d = ch*8 + u;
        int jx = (row & 7) | ((((row >> 3) ^ (d >> 3)) & 7) << 3);
        Vt[d*72 + jx] = vv[u];
      }
    }
    __syncthreads();

    // S = Q K^T  (A = Q-frag, B = K rows as [n][k])
    f32x4 s[4];
#pragma unroll
    for (int f = 0; f < 4; ++f) {
      f16x8 kf0 = *(const f16x8*)&Klds[(f*16 + lr)*72 + lk*8];
      f16x8 kf1 = *(const f16x8*)&Klds[(f*16 + lr)*72 + 32 + lk*8];
      f32x4 z = zf;
      z = __builtin_amdgcn_mfma_f32_16x16x32_f16(qf0, kf0, z, 0, 0, 0);
      z = __builtin_amdgcn_mfma_f32_16x16x32_f16(qf1, kf1, z, 0, 0, 0);
      s[f] = z;
    }

    // scale (+ causal mask on diagonal tile). S layout: col j = lane&15 (+16f), row q = 4*(lane>>4)+r
    if (jt == qt) {
#pragma unroll
      for (int f = 0; f < 4; ++f)
#pragma unroll
        for (int r = 0; r < 4; ++r) {
          int jg = f*16 + lr;
          int qg = wid*16 + lk*4 + r;
          s[f][r] = (jg <= qg) ? s[f][r] * sc : -1e30f;
        }
    } else {
#pragma unroll
      for (int f = 0; f < 4; ++f)
#pragma unroll
        for (int r = 0; r < 4; ++r) s[f][r] *= sc;
    }

    // online softmax (16-lane butterfly across j)
    float alpha[4];
#pragma unroll
    for (int r = 0; r < 4; ++r) {
      float v = fmaxf(fmaxf(s[0][r], s[1][r]), fmaxf(s[2][r], s[3][r]));
      v = fmaxf(v, __shfl_xor(v, 1));
      v = fmaxf(v, __shfl_xor(v, 2));
      v = fmaxf(v, __shfl_xor(v, 4));
      v = fmaxf(v, __shfl_xor(v, 8));
      float mnew = fmaxf(mrow[r], v);
      alpha[r] = exp2f(mrow[r] - mnew);
      mrow[r] = mnew;
    }
#pragma unroll
    for (int r = 0; r < 4; ++r) {
      float sum = 0.f;
#pragma unroll
      for (int f = 0; f < 4; ++f) {
        float p = exp2f(s[f][r] - mrow[r]);
        s[f][r] = p;
        sum += p;
      }
      sum += __shfl_xor(sum, 1);
      sum += __shfl_xor(sum, 2);
      sum += __shfl_xor(sum, 4);
      sum += __shfl_xor(sum, 8);
      lsum[r] = lsum[r] * alpha[r] + sum;
      o[0][r] *= alpha[r]; o[1][r] *= alpha[r]; o[2][r] *= alpha[r]; o[3][r] *= alpha[r];
    }

    // P -> per-wave LDS tile (fix C-layout -> A-frag layout)
#pragma unroll
    for (int f = 0; f < 4; ++f)
#pragma unroll
      for (int r = 0; r < 4; ++r)
        Plds[wid*1152 + (lk*4 + r)*72 + f*16 + lr] = (_Float16)s[f][r];

    // O += P V   (B = Vt[d][j], swizzled blocks)
    f16x8 pf0 = *(const f16x8*)&Plds[wid*1152 + lr*72 + lk*8];
    f16x8 pf1 = *(const f16x8*)&Plds[wid*1152 + lr*72 + 32 + lk*8];
#pragma unroll
    for (int f = 0; f < 4; ++f) {
      int d0 = f*16 + lr;
      int cx = (d0 >> 3) & 7;
      f16x8 vf0 = *(const f16x8*)&Vt[d0*72 + (((0*4 + lk) ^ cx) << 3)];
      f16x8 vf1 = *(const f16x8*)&Vt[d0*72 + (((1*4 + lk) ^ cx) << 3)];
      o[f] = __builtin_amdgcn_mfma_f32_16x16x32_f16(pf0, vf0, o[f], 0, 0, 0);
      o[f] = __builtin_amdgcn_mfma_f32_16x16x32_f16(pf1, vf1, o[f], 0, 0, 0);
    }
  }

  // normalize and write out (O layout: col d = lane&15 (+16f), row q = 4*(lane>>4)+r)
  float inv[4];
#pragma unroll
  for (int r = 0; r < 4; ++r) inv[r] = 1.f / lsum[r];
#pragma unroll
  for (int f = 0; f < 4; ++f) {
    int d = f*16 + lr;
#pragma unroll
    for (int r = 0; r < 4; ++r) {
      int qg = qt*64 + wid*16 + lk*4 + r;
      O[base + (size_t)qg * DD + d] = (_Float16)(o[f][r] * inv[r]);
    }
  }
}

extern "C" void kernel_launch(void* const* d_in, const int* in_sizes, int n_in,
                              void* d_out, int out_size, void* d_ws, size_t ws_size,
                              hipStream_t stream) {
  const float* x  = (const float*)d_in[0];
  const float* Wq = (const float*)d_in[1];
  const float* bq = (const float*)d_in[2];
  const float* Wk = (const float*)d_in[3];
  const float* bk = (const float*)d_in[4];
  const float* Wv = (const float*)d_in[5];
  const float* bv = (const float*)d_in[6];
  const float* Wp = (const float*)d_in[7];
  const float* bp = (const float*)d_in[8];
  float* out = (float*)d_out;

  const size_t XN = (size_t)MM * DD;   // 8,388,608
  const size_t WN = (size_t)DD * DD;   // 1,048,576
  _Float16* ws  = (_Float16*)d_ws;
  _Float16* Xb  = ws;                  // also reused as attention output (Ab)
  _Float16* WqT = ws + XN;
  _Float16* WkT = WqT + WN;
  _Float16* WvT = WkT + WN;
  _Float16* WpT = WvT + WN;
  _Float16* Qb  = WpT + WN;
  _Float16* Kb  = Qb + XN;
  _Float16* Vb  = Kb + XN;
  _Float16* Ab  = Xb;

  cvt_f16<<<dim3((unsigned)(XN/8/256)), 256, 0, stream>>>(x, Xb, (int)(XN/8));
  transpose_cvt<<<dim3(32, 32, 4), dim3(32, 8), 0, stream>>>(Wq, Wk, Wv, Wp,
                                                             WqT, WkT, WvT, WpT);
  gemm_qkv<<<dim3(8, 64, 3), 256, 0, stream>>>(Xb, WqT, WkT, WvT, bq, bk, bv,
                                               Qb, Kb, Vb);
  attn_fwd<<<dim3(32, 64), 256, 0, stream>>>(Qb, Kb, Vb, Ab);
  gemm_proj<<<dim3(8, 64), 256, 0, stream>>>(Ab, WpT, bp, out);
}

// Round 4
// 335.216 us; speedup vs baseline: 1.3640x; 1.3640x over previous
//
#include <hip/hip_runtime.h>
#include <hip/hip_bf16.h>

#define BB 4
#define TT 2048
#define DD 1024
#define HH 16
#define HD 64
#define MM (BB*TT)   // 8192

typedef __attribute__((ext_vector_type(8))) _Float16 f16x8;
typedef __attribute__((ext_vector_type(4))) float f32x4;

static __device__ __forceinline__ void gload_lds16(const void* g, void* l) {
  __builtin_amdgcn_global_load_lds((const __attribute__((address_space(1))) void*)g,
                                   (__attribute__((address_space(3))) void*)l, 16, 0, 0);
}

// ---------------- fp32 -> fp16 conversion, 8 elems/thread ----------------
__global__ __launch_bounds__(256) void cvt_f16(const float* __restrict__ in,
                                               _Float16* __restrict__ out, int n8) {
  int i = blockIdx.x * 256 + threadIdx.x;
  if (i >= n8) return;
  const f32x4* p = (const f32x4*)in;
  f32x4 a = p[2*i];
  f32x4 b = p[2*i+1];
  f16x8 r;
  r[0]=(_Float16)a[0]; r[1]=(_Float16)a[1]; r[2]=(_Float16)a[2]; r[3]=(_Float16)a[3];
  r[4]=(_Float16)b[0]; r[5]=(_Float16)b[1]; r[6]=(_Float16)b[2]; r[7]=(_Float16)b[3];
  *(f16x8*)(out + (size_t)8*i) = r;
}

// ------------- W[k][n] fp32 -> Wt[n][k] fp16 (1024x1024), z picks matrix -------------
__global__ __launch_bounds__(256) void transpose_cvt(
    const float* __restrict__ W0, const float* __restrict__ W1,
    const float* __restrict__ W2, const float* __restrict__ W3,
    _Float16* __restrict__ O0, _Float16* __restrict__ O1,
    _Float16* __restrict__ O2, _Float16* __restrict__ O3) {
  const float* W; _Float16* O;
  switch (blockIdx.z) {
    case 0: W = W0; O = O0; break;
    case 1: W = W1; O = O1; break;
    case 2: W = W2; O = O2; break;
    default: W = W3; O = O3; break;
  }
  __shared__ float tile[32][33];
  int bx = blockIdx.x * 32, by = blockIdx.y * 32;
  int tx = threadIdx.x, ty = threadIdx.y;   // (32, 8)
#pragma unroll
  for (int i = 0; i < 4; i++)
    tile[ty + 8*i][tx] = W[(size_t)(by + ty + 8*i) * DD + bx + tx];
  __syncthreads();
#pragma unroll
  for (int i = 0; i < 4; i++)
    O[(size_t)(bx + ty + 8*i) * DD + by + tx] = (_Float16)tile[tx][ty + 8*i];
}

// ---------------- GEMM: C[M][N] = A[M][K] * Bt[N][K]^T + bias ----------------
// 128x128 tile, BK=32, 4 waves (2x2 of 64x64), 16x16x32 fp16 MFMA.
template<bool OUT_F32>
static __device__ __forceinline__ void gemm_body(
    const _Float16* __restrict__ A, const _Float16* __restrict__ Bt,
    const float* __restrict__ bias, void* __restrict__ Cv) {
  const int K = 1024, N = 1024;
  __shared__ __align__(16) _Float16 Alds[128*32];
  __shared__ __align__(16) _Float16 Blds[128*32];
  int tid = threadIdx.x;
  int wid = tid >> 6, lane = tid & 63;
  int m0 = blockIdx.y * 128, n0 = blockIdx.x * 128;
  int wr = wid >> 1, wc = wid & 1;
  int lr = lane & 15, lk = lane >> 4;

  f32x4 zf = {0.f, 0.f, 0.f, 0.f};
  f32x4 acc[4][4];
#pragma unroll
  for (int m = 0; m < 4; m++)
#pragma unroll
    for (int n = 0; n < 4; n++) acc[m][n] = zf;

  int c0 = wid * 2;
  int srow = c0 * 16 + (lane >> 2);
  int skc  = (lane & 3) * 8;
  const _Float16* gA0 = A  + (size_t)(m0 + srow) * K + skc;
  const _Float16* gA1 = gA0 + 16 * K;
  const _Float16* gB0 = Bt + (size_t)(n0 + srow) * K + skc;
  const _Float16* gB1 = gB0 + 16 * K;
  _Float16* lA0 = Alds + c0 * 512;
  _Float16* lA1 = Alds + (c0 + 1) * 512;
  _Float16* lB0 = Blds + c0 * 512;
  _Float16* lB1 = Blds + (c0 + 1) * 512;

  for (int k0 = 0; k0 < K; k0 += 32) {
    __syncthreads();
    gload_lds16(gA0 + k0, lA0);
    gload_lds16(gA1 + k0, lA1);
    gload_lds16(gB0 + k0, lB0);
    gload_lds16(gB1 + k0, lB1);
    __syncthreads();
    f16x8 af[4], bf[4];
#pragma unroll
    for (int m = 0; m < 4; m++)
      af[m] = *(const f16x8*)&Alds[(wr*64 + m*16 + lr)*32 + lk*8];
#pragma unroll
    for (int n = 0; n < 4; n++)
      bf[n] = *(const f16x8*)&Blds[(wc*64 + n*16 + lr)*32 + lk*8];
#pragma unroll
    for (int m = 0; m < 4; m++)
#pragma unroll
      for (int n = 0; n < 4; n++)
        acc[m][n] = __builtin_amdgcn_mfma_f32_16x16x32_f16(af[m], bf[n], acc[m][n], 0, 0, 0);
  }

#pragma unroll
  for (int n = 0; n < 4; n++) {
    int col = n0 + wc*64 + n*16 + lr;
    float bs = bias[col];
#pragma unroll
    for (int m = 0; m < 4; m++) {
      int row = m0 + wr*64 + m*16 + lk*4;
#pragma unroll
      for (int r = 0; r < 4; r++) {
        float v = acc[m][n][r] + bs;
        if (OUT_F32) ((float*)Cv)[(size_t)(row + r) * N + col] = v;
        else         ((_Float16*)Cv)[(size_t)(row + r) * N + col] = (_Float16)v;
      }
    }
  }
}

__global__ __launch_bounds__(256) void gemm_qkv(
    const _Float16* __restrict__ X,
    const _Float16* __restrict__ WqT, const _Float16* __restrict__ WkT,
    const _Float16* __restrict__ WvT,
    const float* __restrict__ bq, const float* __restrict__ bk,
    const float* __restrict__ bv,
    _Float16* __restrict__ Qo, _Float16* __restrict__ Ko, _Float16* __restrict__ Vo) {
  const _Float16* Bt; const float* bias; _Float16* C;
  if (blockIdx.z == 0)      { Bt = WqT; bias = bq; C = Qo; }
  else if (blockIdx.z == 1) { Bt = WkT; bias = bk; C = Ko; }
  else                      { Bt = WvT; bias = bv; C = Vo; }
  gemm_body<false>(X, Bt, bias, C);
}

__global__ __launch_bounds__(256) void gemm_proj(
    const _Float16* __restrict__ Ain, const _Float16* __restrict__ WpT,
    const float* __restrict__ bp, float* __restrict__ out) {
  gemm_body<true>(Ain, WpT, bp, out);
}

// ---------------- causal flash attention ----------------
// grid (8, 64), 256 threads = 4 waves. Block handles q-tiles {bx, 15-bx} of 128
// rows each (wave owns 32 rows = 2 MFMA frags). KV tiles of 64, double-buffered.
// K: global_load_lds + XOR chunk swizzle (round-1-GEMM-proven mechanics).
// V: round-1-proven Vt[d*72 + jx] scatter layout (block-XOR on j).
__global__ __launch_bounds__(256, 2) void attn_fwd(
    const _Float16* __restrict__ Q, const _Float16* __restrict__ Kg,
    const _Float16* __restrict__ Vg, _Float16* __restrict__ O) {
  // K: [buf][row 0..63][64], LDS[row][c] = K[row][c ^ (row&7)] (pre-swizzled src)
  __shared__ __align__(16) _Float16 Klds[2*4096];
  // V: [buf][d 0..63][72], jx = (j&7) | ((((j>>3) ^ (d>>3)) & 7) << 3)
  __shared__ __align__(16) _Float16 Vt[2*4608];
  // P: per-wave [32][72]
  __shared__ __align__(16) _Float16 Plds[4*32*72];

  const int tid = threadIdx.x;
  const int wid = tid >> 6, lane = tid & 63;
  const int lr = lane & 15, lk = lane >> 4;
  const int bh = blockIdx.y, b = bh >> 4, h = bh & 15;
  const size_t base = (size_t)b * TT * DD + h * HD;
  const float sc = 0.18033688011112042f;   // (1/sqrt(64)) * log2(e)

  // K staging: wave w stages rows 16w..16w+15 (2 calls of 8 rows).
  // lane L -> local row L>>3, lds chunk L&7; global chunk = (L&7) ^ (L>>3).
  const int krow  = 16*wid + (lane >> 3);
  const int kchnk = ((lane & 7) ^ (lane >> 3)) * 8;
  const int kg0 = krow*DD + kchnk, kg1 = (krow+8)*DD + kchnk;
  const int kl0 = 16*wid*64,       kl1 = (16*wid+8)*64;
  // V staging: lane L -> rows krow, krow+8, d-chunk (lane&7)*8.
  const int vch = lane & 7;
  const int vg0 = krow*DD + vch*8, vg1 = (krow+8)*DD + vch*8;

  _Float16* Pw = Plds + wid*32*72;

  for (int qs = 0; qs < 2; ++qs) {
    const int qt = qs ? (15 - (int)blockIdx.x) : (int)blockIdx.x;
    const int jmax = 2*qt + 1;

    // Q fragments in registers (A-frag: row=lane&15, k = lk*8 + 32h)
    f16x8 qf[2][2];
#pragma unroll
    for (int t = 0; t < 2; ++t) {
      const size_t qr = base + (size_t)(qt*128 + wid*32 + t*16 + lr) * DD;
#pragma unroll
      for (int hh2 = 0; hh2 < 2; ++hh2)
        qf[t][hh2] = *(const f16x8*)&Q[qr + hh2*32 + lk*8];
    }

    f32x4 zf = {0.f, 0.f, 0.f, 0.f};
    f32x4 o[2][4];
    float m[2][4], l[2][4];
#pragma unroll
    for (int t = 0; t < 2; ++t)
#pragma unroll
      for (int f = 0; f < 4; ++f) o[t][f] = zf;
#pragma unroll
    for (int t = 0; t < 2; ++t)
#pragma unroll
      for (int r = 0; r < 4; ++r) { m[t][r] = -1e30f; l[t][r] = 0.f; }

    // ---- prologue: stage tile 0 into buf 0 ----
    {
      gload_lds16(Kg + base + kg0, Klds + kl0);
      gload_lds16(Kg + base + kg1, Klds + kl1);
      f16x8 v0 = *(const f16x8*)(Vg + base + vg0);
      f16x8 v1 = *(const f16x8*)(Vg + base + vg1);
#pragma unroll
      for (int u = 0; u < 8; ++u) {
        int d = vch*8 + u;
        int jx0 = (krow & 7)     | ((((krow>>3)     ^ (d>>3)) & 7) << 3);
        int jx1 = ((krow+8) & 7) | (((((krow+8)>>3) ^ (d>>3)) & 7) << 3);
        Vt[d*72 + jx0] = v0[u];
        Vt[d*72 + jx1] = v1[u];
      }
      __syncthreads();
    }

    int bsel = 0;
    for (int jt = 0; jt <= jmax; ++jt) {
      const bool pf = (jt < jmax);
      f16x8 vr0, vr1;
      if (pf) {   // issue next-tile loads (K async to LDS[bsel^1], V to regs)
        const size_t nb = base + (size_t)(jt+1) * 64 * DD;
        _Float16* kd = Klds + (bsel^1)*4096;
        gload_lds16(Kg + nb + kg0, kd + kl0);
        gload_lds16(Kg + nb + kg1, kd + kl1);
        vr0 = *(const f16x8*)(Vg + nb + vg0);
        vr1 = *(const f16x8*)(Vg + nb + vg1);
      }

      // ---- QK^T ----
      const _Float16* Kb = Klds + bsel*4096;
      f32x4 s[2][4];
      __builtin_amdgcn_s_setprio(1);
#pragma unroll
      for (int f = 0; f < 4; ++f) {
        const int row = 16*f + lr;
        f16x8 kf0 = *(const f16x8*)&Kb[row*64 + ((lk    ) ^ (lr & 7))*8];
        f16x8 kf1 = *(const f16x8*)&Kb[row*64 + ((lk + 4) ^ (lr & 7))*8];
#pragma unroll
        for (int t = 0; t < 2; ++t) {
          f32x4 z = zf;
          z = __builtin_amdgcn_mfma_f32_16x16x32_f16(qf[t][0], kf0, z, 0, 0, 0);
          z = __builtin_amdgcn_mfma_f32_16x16x32_f16(qf[t][1], kf1, z, 0, 0, 0);
          s[t][f] = z;
        }
      }
      __builtin_amdgcn_s_setprio(0);

      // ---- scale + causal mask + online softmax ----
#pragma unroll
      for (int t = 0; t < 2; ++t) {
        const int qmin = qt*128 + wid*32 + t*16;
        // mask-free ONLY if tile's max j (64jt+63) < frag's min row.
        if (64*jt + 64 > qmin) {
#pragma unroll
          for (int f = 0; f < 4; ++f)
#pragma unroll
            for (int r = 0; r < 4; ++r) {
              int jg = 64*jt + 16*f + lr;
              int qg = qmin + lk*4 + r;
              s[t][f][r] = (jg <= qg) ? s[t][f][r] * sc : -1e30f;
            }
        } else {
#pragma unroll
          for (int f = 0; f < 4; ++f)
#pragma unroll
            for (int r = 0; r < 4; ++r) s[t][f][r] *= sc;
        }
        float alpha[4];
#pragma unroll
        for (int r = 0; r < 4; ++r) {
          float v = fmaxf(fmaxf(s[t][0][r], s[t][1][r]), fmaxf(s[t][2][r], s[t][3][r]));
          v = fmaxf(v, __shfl_xor(v, 1));
          v = fmaxf(v, __shfl_xor(v, 2));
          v = fmaxf(v, __shfl_xor(v, 4));
          v = fmaxf(v, __shfl_xor(v, 8));
          float mn = fmaxf(m[t][r], v);
          alpha[r] = exp2f(m[t][r] - mn);
          m[t][r] = mn;
        }
#pragma unroll
        for (int r = 0; r < 4; ++r) {
          float sum = 0.f;
#pragma unroll
          for (int f = 0; f < 4; ++f) {
            float p = exp2f(s[t][f][r] - m[t][r]);
            s[t][f][r] = p;
            sum += p;
          }
          sum += __shfl_xor(sum, 1);
          sum += __shfl_xor(sum, 2);
          sum += __shfl_xor(sum, 4);
          sum += __shfl_xor(sum, 8);
          l[t][r] = l[t][r] * alpha[r] + sum;
#pragma unroll
          for (int f = 0; f < 4; ++f) o[t][f][r] *= alpha[r];
        }
        // P -> per-wave LDS (C-layout -> A-frag layout)
#pragma unroll
        for (int f = 0; f < 4; ++f)
#pragma unroll
          for (int r = 0; r < 4; ++r)
            Pw[(t*16 + lk*4 + r)*72 + f*16 + lr] = (_Float16)s[t][f][r];
      }

      // ---- P A-frags ----
      f16x8 pa[2][2];
#pragma unroll
      for (int t = 0; t < 2; ++t)
#pragma unroll
        for (int hh2 = 0; hh2 < 2; ++hh2)
          pa[t][hh2] = *(const f16x8*)&Pw[(t*16 + lr)*72 + hh2*32 + lk*8];

      // ---- O += P V  (V B-frags from round-1-proven Vt layout) ----
      const _Float16* Vb = Vt + bsel*4608;
      __builtin_amdgcn_s_setprio(1);
#pragma unroll
      for (int f = 0; f < 4; ++f) {
        int d0 = f*16 + lr;
        int cx = (d0 >> 3) & 7;
        f16x8 vf0 = *(const f16x8*)&Vb[d0*72 + (((0*4 + lk) ^ cx) << 3)];
        f16x8 vf1 = *(const f16x8*)&Vb[d0*72 + (((1*4 + lk) ^ cx) << 3)];
#pragma unroll
        for (int t = 0; t < 2; ++t) {
          o[t][f] = __builtin_amdgcn_mfma_f32_16x16x32_f16(pa[t][0], vf0, o[t][f], 0, 0, 0);
          o[t][f] = __builtin_amdgcn_mfma_f32_16x16x32_f16(pa[t][1], vf1, o[t][f], 0, 0, 0);
        }
      }
      __builtin_amdgcn_s_setprio(0);

      // ---- scatter next V tile into alternate buffer ----
      if (pf) {
        _Float16* vd = Vt + (bsel^1)*4608;
#pragma unroll
        for (int u = 0; u < 8; ++u) {
          int d = vch*8 + u;
          int jx0 = (krow & 7)     | ((((krow>>3)     ^ (d>>3)) & 7) << 3);
          int jx1 = ((krow+8) & 7) | (((((krow+8)>>3) ^ (d>>3)) & 7) << 3);
          vd[d*72 + jx0] = vr0[u];
          vd[d*72 + jx1] = vr1[u];
        }
      }
      __syncthreads();
      bsel ^= 1;
    }

    // ---- finalize + write O ----
#pragma unroll
    for (int t = 0; t < 2; ++t) {
      float inv[4];
#pragma unroll
      for (int r = 0; r < 4; ++r) inv[r] = 1.f / l[t][r];
#pragma unroll
      for (int f = 0; f < 4; ++f) {
        int d = 16*f + lr;
#pragma unroll
        for (int r = 0; r < 4; ++r) {
          int qg = qt*128 + wid*32 + t*16 + lk*4 + r;
          O[base + (size_t)qg * DD + d] = (_Float16)(o[t][f][r] * inv[r]);
        }
      }
    }
    __syncthreads();
  }
}

extern "C" void kernel_launch(void* const* d_in, const int* in_sizes, int n_in,
                              void* d_out, int out_size, void* d_ws, size_t ws_size,
                              hipStream_t stream) {
  const float* x  = (const float*)d_in[0];
  const float* Wq = (const float*)d_in[1];
  const float* bq = (const float*)d_in[2];
  const float* Wk = (const float*)d_in[3];
  const float* bk = (const float*)d_in[4];
  const float* Wv = (const float*)d_in[5];
  const float* bv = (const float*)d_in[6];
  const float* Wp = (const float*)d_in[7];
  const float* bp = (const float*)d_in[8];
  float* out = (float*)d_out;

  const size_t XN = (size_t)MM * DD;   // 8,388,608
  const size_t WN = (size_t)DD * DD;   // 1,048,576
  _Float16* ws  = (_Float16*)d_ws;
  _Float16* Xb  = ws;                  // also reused as attention output (Ab)
  _Float16* WqT = ws + XN;
  _Float16* WkT = WqT + WN;
  _Float16* WvT = WkT + WN;
  _Float16* WpT = WvT + WN;
  _Float16* Qb  = WpT + WN;
  _Float16* Kb  = Qb + XN;
  _Float16* Vb  = Kb + XN;
  _Float16* Ab  = Xb;

  cvt_f16<<<dim3((unsigned)(XN/8/256)), 256, 0, stream>>>(x, Xb, (int)(XN/8));
  transpose_cvt<<<dim3(32, 32, 4), dim3(32, 8), 0, stream>>>(Wq, Wk, Wv, Wp,
                                                             WqT, WkT, WvT, WpT);
  gemm_qkv<<<dim3(8, 64, 3), 256, 0, stream>>>(Xb, WqT, WkT, WvT, bq, bk, bv,
                                               Qb, Kb, Vb);
  attn_fwd<<<dim3(8, 64), 256, 0, stream>>>(Qb, Kb, Vb, Ab);
  gemm_proj<<<dim3(8, 64), 256, 0, stream>>>(Ab, WpT, bp, out);
}